// Round 11
// baseline (487.911 us; speedup 1.0000x reference)
//
#include <hip/hip_runtime.h>
#include <hip/hip_bf16.h>
#include <hip/hip_cooperative_groups.h>
#include <math.h>

namespace cg = cooperative_groups;

// MambaBlock3D: B=1, C=128, L=24^3=13824, D_INNER=256, D_STATE=16, D_CONV=4, DT_RANK=8
// Token-major bf16 activations, MFMA GEMMs, fused cooperative fp32 scan.

constexpr int LQ = 13824;
constexpr int NC = 216;     // scan chunks (CH=64)
constexpr int CH = 64;      // chunk length
constexpr int NB = 108;     // 128-l GEMM tiles
constexpr int DI = 256;
constexpr int DS = 16;

typedef __attribute__((ext_vector_type(8))) short short8v;   // 8 bf16 = 4 VGPR
typedef __attribute__((ext_vector_type(4))) float float4v;

__device__ __forceinline__ ushort f2bf(float f) {
  uint u = __float_as_uint(f);
  u += 0x7FFFu + ((u >> 16) & 1u);          // round-to-nearest-even
  return (ushort)(u >> 16);
}
__device__ __forceinline__ float bf2f(ushort u) {
  return __uint_as_float(((uint)u) << 16);
}
// async global->LDS, 16 bytes per lane; dest must be linear (base + lane*16)
__device__ __forceinline__ void gl_lds16(const ushort* g, ushort* l) {
  __builtin_amdgcn_global_load_lds(
      (const __attribute__((address_space(1))) void*)g,
      (__attribute__((address_space(3))) void*)l, 16, 0, 0);
}

template<int CTRL>
__device__ __forceinline__ float dpp_add(float x) {
  int y = __builtin_amdgcn_update_dpp(0, __float_as_int(x), CTRL, 0xF, 0xF, true);
  return x + __int_as_float(y);
}
// quad butterfly: all 4 lanes of each quad get the quad sum
__device__ __forceinline__ float quad_reduce(float t) {
  t = dpp_add<0xB1>(t);    // quad_perm xor1
  t = dpp_add<0x4E>(t);    // quad_perm xor2
  return t;
}
__device__ __forceinline__ float softplus_f(float x) {
  return (x > 20.f) ? x : log1pf(__expf(x));
}

// ---------------- weight prep: bf16 casts + W_combo = Wdt @ Wxp[0:8] ----------------
// wbf_xp2 (320 x 256): rows 0..15 = B rows, 16..31 = C rows, 32..287 = dt_lin combo, 288..319 = 0.
__global__ __launch_bounds__(256) void prep_w2(const float* __restrict__ w_in,
    const float* __restrict__ w_xp, const float* __restrict__ w_dt,
    const float* __restrict__ w_out,
    ushort* __restrict__ b_in, ushort* __restrict__ b_xp2, ushort* __restrict__ b_out) {
  int idx = blockIdx.x * 256 + threadIdx.x;
  if (idx < 65536) {
    b_in[idx] = f2bf(w_in[idx]);
  } else if (idx < 65536 + 8192) {               // BC rows
    int j = idx - 65536; int r = j >> 8, k = j & 255;
    b_xp2[j] = f2bf(w_xp[(8 + r) * 256 + k]);
  } else if (idx < 65536 + 8192 + 65536) {       // combo rows
    int j = idx - (65536 + 8192); int d = j >> 8, k = j & 255;
    float acc = 0.f;
    #pragma unroll
    for (int r = 0; r < 8; ++r) acc += w_dt[d * 8 + r] * w_xp[r * 256 + k];
    b_xp2[8192 + j] = f2bf(acc);
  } else if (idx < 65536 + 8192 + 65536 + 8192) {  // zero pad rows
    b_xp2[73728 + (idx - 139264)] = 0;
  } else if (idx < 180224) {
    int j = idx - 147456;
    b_out[j] = f2bf(w_out[j]);
  }
}

// ---------------- LayerNorm: x (C,L) fp32 -> tn (L,128) bf16, x cached in regs ----------------
__global__ __launch_bounds__(256) void ln_t(const float* __restrict__ x,
    const float* __restrict__ lnw, const float* __restrict__ lnb,
    ushort* __restrict__ tn) {
  __shared__ float red[64][8];
  __shared__ float stat[64][2];
  __shared__ ushort T[64][136];
  const int t = threadIdx.x;
  const int l = t & 63, q = t >> 6;
  const int l0 = blockIdx.x * 64;
  float vals[32];
  float sum = 0.f, sq = 0.f;
  #pragma unroll 8
  for (int cc = 0; cc < 32; ++cc) {
    float v = x[(size_t)(q * 32 + cc) * LQ + l0 + l];
    vals[cc] = v;
    sum += v; sq += v * v;
  }
  red[l][q] = sum; red[l][4 + q] = sq;
  __syncthreads();
  if (t < 64) {
    float s  = red[t][0] + red[t][1] + red[t][2] + red[t][3];
    float s2 = red[t][4] + red[t][5] + red[t][6] + red[t][7];
    float mu = s * (1.f / 128.f);
    float var = s2 * (1.f / 128.f) - mu * mu;
    stat[t][0] = mu; stat[t][1] = rsqrtf(var + 1e-5f);
  }
  __syncthreads();
  float mu = stat[l][0], rs = stat[l][1];
  #pragma unroll 8
  for (int cc = 0; cc < 32; ++cc) {
    int c = q * 32 + cc;
    T[l][c] = f2bf((vals[cc] - mu) * rs * lnw[c] + lnb[c]);
  }
  __syncthreads();
  int row = t >> 2, seg = t & 3;
  #pragma unroll
  for (int j = 0; j < 4; ++j) {
    short8v v = *(const short8v*)&T[row][seg * 32 + j * 8];
    *(short8v*)&tn[(size_t)(l0 + row) * 128 + seg * 32 + j * 8] = v;
  }
}

// ---------------- MFMA GEMM (token-major out): 128l x 64m tile, gl_lds dbuf B ----------------
template<int K, int MV, int BSTR, int CSTR>
__global__ __launch_bounds__(256) void gemm_tok(
    const ushort* __restrict__ Wb,
    const ushort* __restrict__ Act,
    ushort* __restrict__ Out) {
  constexpr int KO = K / 8;
  __shared__ ushort As[64 * K];
  __shared__ ushort Bs[2][128 * 64];
  const int tid = threadIdx.x;
  const int l0 = blockIdx.x * 128;
  const int m0 = blockIdx.y * 64;
  #pragma unroll
  for (int i = 0; i < (64 * KO) / 256; ++i) {
    int cid = i * 256 + tid;
    int m = cid / KO, oct = cid % KO;
    short8v v = *(const short8v*)&Wb[(size_t)(m0 + m) * K + oct * 8];
    *(short8v*)&As[m * K + ((oct ^ (m & 7)) * 8)] = v;
  }
  #pragma unroll
  for (int i = 0; i < 4; ++i) {
    int cid = i * 256 + tid;
    int l = cid >> 3, oct = (cid & 7) ^ (l & 7);
    gl_lds16(&Act[(size_t)(l0 + l) * BSTR + oct * 8], &Bs[0][cid * 8]);
  }
  float4v acc[4][2];
  #pragma unroll
  for (int a = 0; a < 4; ++a)
    #pragma unroll
    for (int b = 0; b < 2; ++b) acc[a][b] = (float4v)0.f;
  const int w = tid >> 6, lane = tid & 63;
  const int r = lane & 15, g = lane >> 4;
  int buf = 0;
  __syncthreads();
  for (int k0 = 0; k0 < K; k0 += 64) {
    if (k0 + 64 < K) {
      #pragma unroll
      for (int i = 0; i < 4; ++i) {
        int cid = i * 256 + tid;
        int l = cid >> 3, oct = (cid & 7) ^ (l & 7);
        gl_lds16(&Act[(size_t)(l0 + l) * BSTR + (k0 + 64) + oct * 8],
                 &Bs[buf ^ 1][cid * 8]);
      }
    }
    const ushort* bp = Bs[buf];
    #pragma unroll
    for (int kk = 0; kk < 2; ++kk) {
      short8v af[4], bfv[2];
      int ko = (k0 >> 3) + kk * 4 + g;
      #pragma unroll
      for (int mf = 0; mf < 4; ++mf) {
        int row = mf * 16 + r;
        af[mf] = *(const short8v*)&As[row * K + ((ko ^ (row & 7)) * 8)];
      }
      int kob = kk * 4 + g;
      #pragma unroll
      for (int nf = 0; nf < 2; ++nf) {
        int row = w * 32 + nf * 16 + r;
        bfv[nf] = *(const short8v*)&bp[row * 64 + ((kob ^ (row & 7)) * 8)];
      }
      #pragma unroll
      for (int mf = 0; mf < 4; ++mf)
        #pragma unroll
        for (int nf = 0; nf < 2; ++nf)
          acc[mf][nf] = __builtin_amdgcn_mfma_f32_16x16x32_bf16(af[mf], bfv[nf], acc[mf][nf], 0, 0, 0);
    }
    __syncthreads();
    buf ^= 1;
  }
  #pragma unroll
  for (int mf = 0; mf < 4; ++mf) {
    #pragma unroll
    for (int nf = 0; nf < 2; ++nf) {
      int l = w * 32 + nf * 16 + r;
      int m = mf * 16 + g * 4;
      ushort u0 = f2bf(acc[mf][nf][0]), u1 = f2bf(acc[mf][nf][1]);
      ushort u2 = f2bf(acc[mf][nf][2]), u3 = f2bf(acc[mf][nf][3]);
      uint2 pk = make_uint2((uint)u0 | ((uint)u1 << 16), (uint)u2 | ((uint)u3 << 16));
      int oct = (m >> 3) ^ (l & 7);
      *(uint2*)&Bs[0][l * 64 + oct * 8 + (g & 1) * 4] = pk;
    }
  }
  __syncthreads();
  #pragma unroll
  for (int i = 0; i < 4; ++i) {
    int cid = i * 256 + tid;
    int row = cid >> 3, oct = cid & 7;
    if (oct * 8 < MV) {
      short8v v = *(const short8v*)&Bs[0][row * 64 + ((oct ^ (row & 7)) * 8)];
      *(short8v*)&Out[(size_t)(l0 + row) * CSTR + m0 + oct * 8] = v;
    }
  }
}

// ---------------- out_proj GEMM (swapped operands) + fp32 residual ----------------
__global__ __launch_bounds__(256) void gemm_out_k(
    const ushort* __restrict__ Wb,
    const ushort* __restrict__ Yg,    // 16 slabs of (L,16) bf16
    const float* __restrict__ X,
    float* __restrict__ Out) {
  __shared__ ushort Ay[2][128 * 64];
  __shared__ ushort Bw[64 * 256];
  const int tid = threadIdx.x;
  const int l0 = blockIdx.x * 128;
  const int c0 = blockIdx.y * 64;
  const int w = tid >> 6, lane = tid & 63;
  const int r = lane & 15, g = lane >> 4;
  #pragma unroll
  for (int i = 0; i < 8; ++i) {
    int cid = i * 256 + tid;
    int row = cid >> 5, oct = cid & 31;
    short8v vb = *(const short8v*)&Wb[(size_t)(c0 + row) * 256 + oct * 8];
    *(short8v*)&Bw[row * 256 + ((oct ^ (row & 7)) * 8)] = vb;
  }
  #pragma unroll
  for (int i = 0; i < 4; ++i) {
    int cid = i * 256 + tid;
    int row = cid >> 3, oct = (cid & 7) ^ (row & 7);
    gl_lds16(&Yg[((size_t)(oct >> 1) * LQ + l0 + row) * 16 + (oct & 1) * 8],
             &Ay[0][cid * 8]);
  }
  float4v acc[2][4];
  #pragma unroll
  for (int a = 0; a < 2; ++a)
    #pragma unroll
    for (int b = 0; b < 4; ++b) acc[a][b] = (float4v)0.f;
  int buf = 0;
  __syncthreads();
  for (int k0 = 0; k0 < 256; k0 += 64) {
    if (k0 + 64 < 256) {
      int ks = (k0 + 64) >> 4;
      #pragma unroll
      for (int i = 0; i < 4; ++i) {
        int cid = i * 256 + tid;
        int row = cid >> 3, oct = (cid & 7) ^ (row & 7);
        gl_lds16(&Yg[((size_t)(ks + (oct >> 1)) * LQ + l0 + row) * 16 + (oct & 1) * 8],
                 &Ay[buf ^ 1][cid * 8]);
      }
    }
    const ushort* ap = Ay[buf];
    #pragma unroll
    for (int kk = 0; kk < 2; ++kk) {
      int kob = kk * 4 + g;
      int ko = (k0 >> 3) + kob;
      short8v af[2], bfv[4];
      #pragma unroll
      for (int mf = 0; mf < 2; ++mf) {
        int row = w * 32 + mf * 16 + r;
        af[mf] = *(const short8v*)&ap[row * 64 + ((kob ^ (row & 7)) * 8)];
      }
      #pragma unroll
      for (int nf = 0; nf < 4; ++nf) {
        int row = nf * 16 + r;
        bfv[nf] = *(const short8v*)&Bw[row * 256 + ((ko ^ (row & 7)) * 8)];
      }
      #pragma unroll
      for (int mf = 0; mf < 2; ++mf)
        #pragma unroll
        for (int nf = 0; nf < 4; ++nf)
          acc[mf][nf] = __builtin_amdgcn_mfma_f32_16x16x32_bf16(af[mf], bfv[nf], acc[mf][nf], 0, 0, 0);
    }
    __syncthreads();
    buf ^= 1;
  }
  #pragma unroll
  for (int mf = 0; mf < 2; ++mf) {
    #pragma unroll
    for (int nf = 0; nf < 4; ++nf) {
      int c = c0 + nf * 16 + r;
      int l = l0 + w * 32 + mf * 16 + g * 4;
      size_t off = (size_t)c * LQ + l;
      float4 rv = *(const float4*)&X[off];
      float4 o = make_float4(acc[mf][nf][0] + rv.x, acc[mf][nf][1] + rv.y,
                             acc[mf][nf][2] + rv.z, acc[mf][nf][3] + rv.w);
      *(float4*)&Out[off] = o;
    }
  }
}

// ---------------- vectorized causal conv (k=4) + SiLU ----------------
__global__ __launch_bounds__(256) void conv2(const ushort* __restrict__ xz,
    const float* __restrict__ cw, const float* __restrict__ cb,
    ushort* __restrict__ xa) {
  const int tid = threadIdx.x;
  const int d0 = (tid & 31) * 8;
  const int l0 = blockIdx.x * 32 + (tid >> 5) * 4;
  float w0[8], w1[8], w2[8], w3[8], bb[8];
  #pragma unroll
  for (int j = 0; j < 8; ++j) {
    float4 wv = *(const float4*)&cw[(d0 + j) * 4];
    w0[j] = wv.x; w1[j] = wv.y; w2[j] = wv.z; w3[j] = wv.w;
    bb[j] = cb[d0 + j];
  }
  float rbuf[7][8];
  #pragma unroll
  for (int t = 0; t < 7; ++t) {
    int ls = l0 - 3 + t;
    if (ls >= 0) {
      short8v v = *(const short8v*)&xz[(size_t)ls * 512 + d0];
      #pragma unroll
      for (int j = 0; j < 8; ++j) rbuf[t][j] = bf2f((ushort)v[j]);
    } else {
      #pragma unroll
      for (int j = 0; j < 8; ++j) rbuf[t][j] = 0.f;
    }
  }
  #pragma unroll
  for (int i = 0; i < 4; ++i) {
    short8v ov;
    #pragma unroll
    for (int j = 0; j < 8; ++j) {
      float acc = bb[j] + w0[j] * rbuf[i][j] + w1[j] * rbuf[i + 1][j]
                        + w2[j] * rbuf[i + 2][j] + w3[j] * rbuf[i + 3][j];
      ov[j] = (short)f2bf(acc / (1.f + __expf(-acc)));
    }
    *(short8v*)&xa[(size_t)(l0 + i) * 256 + d0] = ov;
  }
}

// ---------------- fused cooperative scan: local scan + combine + correction + gate ----------------
// Grid (NC, 4) = 864 blocks, 256 threads, 33.8 KB LDS -> 4 blocks/CU (capacity 1024), co-resident.
__global__ __launch_bounds__(256, 4) void scan_fused(const ushort* __restrict__ xdbl,
    const ushort* __restrict__ xa, const ushort* __restrict__ xz,
    const float* __restrict__ bias, const float* __restrict__ A_log,
    const float* __restrict__ Dp, float* __restrict__ Stot, float* __restrict__ Hc,
    float* __restrict__ Hin, ushort* __restrict__ yg) {
  __shared__ uint  duL[64 * 64];    // [i][d] (dt lo | dt*xa hi)        16 KB
  __shared__ float bcL[64 * 32];    // [i][B0..15 C16..31] fp32          8 KB
  __shared__ ushort ylds[64 * 72];  // [i][d] y bf16 (pad 72)          9.2 KB
  cg::grid_group gridg = cg::this_grid();
  const int tid = threadIdx.x;
  const int c = blockIdx.x, dg = blockIdx.y;
  const int dloc = tid >> 2, sq = tid & 3;
  const int d = dg * 64 + dloc;
  const int lb = c * CH;
  float4v A, h;
  #pragma unroll
  for (int k = 0; k < 4; ++k) {
    A[k] = -__expf(A_log[d * 16 + sq * 4 + k]);
    h[k] = 0.f;
  }
  float S = 0.f;
  // ---- phase 1: stage + local scan ----
  {   // stage (dt, dt*xa): thread = (row=dloc as l-row, part=sq), 16 d each
    const int doff = dg * 64 + sq * 16;
    const ushort* xr = xdbl + (size_t)(lb + dloc) * 320 + 32 + doff;
    const ushort* xar = xa + (size_t)(lb + dloc) * 256 + doff;
    short8v d0 = *(const short8v*)xr;
    short8v d1 = *(const short8v*)(xr + 8);
    short8v x0 = *(const short8v*)xar;
    short8v x1 = *(const short8v*)(xar + 8);
    uint pk[16];
    #pragma unroll
    for (int j = 0; j < 8; ++j) {
      float sp = softplus_f(bf2f((ushort)d0[j]) + bias[doff + j]);
      pk[j] = (uint)f2bf(sp) | ((uint)f2bf(sp * bf2f((ushort)x0[j])) << 16);
      float sp2 = softplus_f(bf2f((ushort)d1[j]) + bias[doff + 8 + j]);
      pk[8 + j] = (uint)f2bf(sp2) | ((uint)f2bf(sp2 * bf2f((ushort)x1[j])) << 16);
    }
    uint4* dst = (uint4*)&duL[dloc * 64 + sq * 16];
    #pragma unroll
    for (int j = 0; j < 4; ++j)
      dst[j] = make_uint4(pk[4 * j], pk[4 * j + 1], pk[4 * j + 2], pk[4 * j + 3]);
  }
  if (tid < 128) {  // stage B, C as fp32
    int row = tid >> 1, half = tid & 1;
    const ushort* xr = xdbl + (size_t)(lb + row) * 320;
    short8v bv = *(const short8v*)(xr + half * 8);
    short8v cv = *(const short8v*)(xr + 16 + half * 8);
    float* bd = &bcL[row * 32 + half * 8];
    float* cd = &bcL[row * 32 + 16 + half * 8];
    #pragma unroll
    for (int j = 0; j < 8; ++j) {
      bd[j] = bf2f((ushort)bv[j]);
      cd[j] = bf2f((ushort)cv[j]);
    }
  }
  __syncthreads();
  #pragma unroll 4
  for (int i = 0; i < CH; ++i) {
    uint pv = duL[i * 64 + dloc];
    float dtv = __uint_as_float(pv << 16);
    float dxv = __uint_as_float(pv & 0xffff0000u);
    S += dtv;
    float4v Bv = *(const float4v*)&bcL[i * 32 + sq * 4];
    float4v Cv = *(const float4v*)&bcL[i * 32 + 16 + sq * 4];
    float t = 0.f;
    #pragma unroll
    for (int k = 0; k < 4; ++k) {
      float a = __expf(dtv * A[k]);
      h[k] = fmaf(a, h[k], dxv * Bv[k]);
      t = fmaf(h[k], Cv[k], t);
    }
    t = quad_reduce(t);
    if (sq == 0) ylds[i * 72 + dloc] = f2bf(t);
  }
  *(float4*)&Hc[(size_t)(c * 256 + d) * 16 + sq * 4] = make_float4(h[0], h[1], h[2], h[3]);
  if (sq == 0) Stot[c * 256 + d] = S;
  __threadfence();
  gridg.sync();
  // ---- phase 2: serial combine, 16 blocks (4096 threads) ----
  if (blockIdx.x < 4) {
    int t = (blockIdx.x * 4 + dg) * 256 + tid;   // d*16 + s over 4096
    int dd = t >> 4;
    float Ac = -__expf(A_log[t]);
    float hh = 0.f;
    for (int cb = 0; cb < NC; cb += 8) {
      float a[8], b[8];
      #pragma unroll
      for (int j = 0; j < 8; ++j) {
        a[j] = Stot[(cb + j) * 256 + dd];
        b[j] = Hc[(size_t)(cb + j) * 4096 + t];
      }
      #pragma unroll
      for (int j = 0; j < 8; ++j) {
        Hin[(size_t)(cb + j) * 4096 + t] = hh;
        hh = fmaf(__expf(Ac * a[j]), hh, b[j]);
      }
    }
  }
  __threadfence();
  gridg.sync();
  // ---- phase 3: correction (dt, C straight from live LDS) ----
  float4v hin;
  {
    float4 hv = *(const float4*)&Hin[(size_t)(c * 256 + d) * 16 + sq * 4];
    hin[0] = hv.x; hin[1] = hv.y; hin[2] = hv.z; hin[3] = hv.w;
  }
  float S2 = 0.f;
  #pragma unroll 4
  for (int i = 0; i < CH; ++i) {
    uint pv = duL[i * 64 + dloc];
    float dtv = __uint_as_float(pv << 16);
    S2 += dtv;
    float4v Cv = *(const float4v*)&bcL[i * 32 + 16 + sq * 4];
    float t = 0.f;
    #pragma unroll
    for (int k = 0; k < 4; ++k)
      t = fmaf(__expf(A[k] * S2), hin[k] * Cv[k], t);
    t = quad_reduce(t);
    if (sq == 0) {
      int yi = i * 72 + dloc;
      ylds[yi] = f2bf(bf2f(ylds[yi]) + t);
    }
  }
  __syncthreads();
  {   // flush: y = (ylocal+corr + xa*D) * silu(z) -> yg slabs
    int slab = tid >> 6, row = tid & 63;
    const int doff = dg * 64 + slab * 16;
    size_t sl = ((size_t)(dg * 4 + slab) * LQ + lb + row) * 16;
    short8v y0 = *(const short8v*)&ylds[row * 72 + slab * 16];
    short8v y1 = *(const short8v*)&ylds[row * 72 + slab * 16 + 8];
    const ushort* xav = xa + (size_t)(lb + row) * 256 + doff;
    short8v x0 = *(const short8v*)xav;
    short8v x1 = *(const short8v*)(xav + 8);
    const ushort* zvp = xz + (size_t)(lb + row) * 512 + 256 + doff;
    short8v z0 = *(const short8v*)zvp;
    short8v z1 = *(const short8v*)(zvp + 8);
    short8v o0, o1;
    #pragma unroll
    for (int j = 0; j < 8; ++j) {
      float v0 = bf2f((ushort)y0[j]) + bf2f((ushort)x0[j]) * Dp[doff + j];
      float zf0 = bf2f((ushort)z0[j]);
      o0[j] = (short)f2bf(v0 * (zf0 / (1.f + __expf(-zf0))));
      float v1 = bf2f((ushort)y1[j]) + bf2f((ushort)x1[j]) * Dp[doff + 8 + j];
      float zf1 = bf2f((ushort)z1[j]);
      o1[j] = (short)f2bf(v1 * (zf1 / (1.f + __expf(-zf1))));
    }
    *(short8v*)&yg[sl] = o0;
    *(short8v*)&yg[sl + 8] = o1;
  }
}

extern "C" void kernel_launch(void* const* d_in, const int* in_sizes, int n_in,
                              void* d_out, int out_size, void* d_ws, size_t ws_size,
                              hipStream_t stream) {
  const float* x         = (const float*)d_in[0];
  const float* ln_w      = (const float*)d_in[1];
  const float* ln_b      = (const float*)d_in[2];
  const float* in_proj_w = (const float*)d_in[3];
  const float* conv_w    = (const float*)d_in[4];
  const float* conv_b    = (const float*)d_in[5];
  const float* x_proj_w  = (const float*)d_in[6];
  const float* dt_proj_w = (const float*)d_in[7];
  const float* dt_proj_b = (const float*)d_in[8];
  const float* A_log     = (const float*)d_in[9];
  const float* D_param   = (const float*)d_in[10];
  const float* out_proj_w= (const float*)d_in[11];
  float* out = (float*)d_out;

  char* ws = (char*)d_ws;
  ushort* wbf_in  = (ushort*)(ws + 0);           // 512x128
  ushort* wbf_xp2 = (ushort*)(ws + 131072);      // 320x256
  ushort* wbf_out = (ushort*)(ws + 294912);      // 128x256
  float*  Hin     = (float*)(ws + 360448);       // 216x4096
  float*  Hc      = (float*)(ws + 3899392);      // 216x4096
  float*  Stot    = (float*)(ws + 7438336);      // 216x256
  ushort* tn_t    = (ushort*)(ws + 7659520);     // (L,128)
  ushort* xz_t    = (ushort*)(ws + 11198464);    // (L,512)
  ushort* xa_t    = (ushort*)(ws + 25354240);    // (L,256)
  ushort* xdbl_t  = (ushort*)(ws + 32432128);    // (L,320): B 0..15, C 16..31, dt_lin 32..287
  ushort* yg_t    = (ushort*)(ws + 41279488);    // 16 slabs (L,16)

  prep_w2<<<704, 256, 0, stream>>>(in_proj_w, x_proj_w, dt_proj_w, out_proj_w,
                                   wbf_in, wbf_xp2, wbf_out);
  ln_t<<<LQ / 64, 256, 0, stream>>>(x, ln_w, ln_b, tn_t);
  gemm_tok<128, 64, 128, 512><<<dim3(NB, 8), 256, 0, stream>>>(wbf_in, tn_t, xz_t);
  conv2<<<LQ / 32, 256, 0, stream>>>(xz_t, conv_w, conv_b, xa_t);
  gemm_tok<256, 64, 256, 320><<<dim3(NB, 5), 256, 0, stream>>>(wbf_xp2, xa_t, xdbl_t);
  {
    void* args[] = {(void*)&xdbl_t, (void*)&xa_t, (void*)&xz_t, (void*)&dt_proj_b,
                    (void*)&A_log, (void*)&D_param, (void*)&Stot, (void*)&Hc,
                    (void*)&Hin, (void*)&yg_t};
    hipLaunchCooperativeKernel((void*)scan_fused, dim3(NC, 4), dim3(256),
                               args, 0, stream);
  }
  gemm_out_k<<<dim3(NB, 2), 256, 0, stream>>>(wbf_out, yg_t, x, out);
}

// Round 12
// 203.012 us; speedup vs baseline: 2.4034x; 2.4034x over previous
//
#include <hip/hip_runtime.h>
#include <hip/hip_bf16.h>
#include <math.h>

// MambaBlock3D: B=1, C=128, L=24^3=13824, D_INNER=256, D_STATE=16, D_CONV=4, DT_RANK=8
// Token-major bf16 activations, MFMA GEMMs (conv fused into in_proj), fp32 scan.

constexpr int LQ = 13824;
constexpr int NC = 216;     // scan chunks (CH=64)
constexpr int CH = 64;      // chunk length
constexpr int NB = 108;     // 128-l GEMM tiles
constexpr int DI = 256;
constexpr int DS = 16;

typedef __attribute__((ext_vector_type(8))) short short8v;   // 8 bf16 = 4 VGPR
typedef __attribute__((ext_vector_type(4))) float float4v;

__device__ __forceinline__ ushort f2bf(float f) {
  uint u = __float_as_uint(f);
  u += 0x7FFFu + ((u >> 16) & 1u);          // round-to-nearest-even
  return (ushort)(u >> 16);
}
__device__ __forceinline__ float bf2f(ushort u) {
  return __uint_as_float(((uint)u) << 16);
}
// async global->LDS, 16 bytes per lane; dest must be linear (base + lane*16)
__device__ __forceinline__ void gl_lds16(const ushort* g, ushort* l) {
  __builtin_amdgcn_global_load_lds(
      (const __attribute__((address_space(1))) void*)g,
      (__attribute__((address_space(3))) void*)l, 16, 0, 0);
}

template<int CTRL>
__device__ __forceinline__ float dpp_add(float x) {
  int y = __builtin_amdgcn_update_dpp(0, __float_as_int(x), CTRL, 0xF, 0xF, true);
  return x + __int_as_float(y);
}
// quad butterfly: all 4 lanes of each quad get the quad sum
__device__ __forceinline__ float quad_reduce(float t) {
  t = dpp_add<0xB1>(t);    // quad_perm xor1
  t = dpp_add<0x4E>(t);    // quad_perm xor2
  return t;
}
__device__ __forceinline__ float softplus_f(float x) {
  return (x > 20.f) ? x : log1pf(__expf(x));
}

// ---------------- prep (blocks 0..703) + LayerNorm (blocks 704..919) ----------------
// wbf_xp2 (320 x 256): rows 0..15 = B rows, 16..31 = C rows, 32..287 = dt_lin combo, 288..319 = 0.
__global__ __launch_bounds__(256) void prep_ln(const float* __restrict__ w_in,
    const float* __restrict__ w_xp, const float* __restrict__ w_dt,
    const float* __restrict__ w_out,
    const float* __restrict__ x, const float* __restrict__ lnw,
    const float* __restrict__ lnb,
    ushort* __restrict__ b_in, ushort* __restrict__ b_xp2, ushort* __restrict__ b_out,
    ushort* __restrict__ tn) {
  if (blockIdx.x < 704) {
    int idx = blockIdx.x * 256 + threadIdx.x;
    if (idx < 65536) {
      b_in[idx] = f2bf(w_in[idx]);
    } else if (idx < 65536 + 8192) {               // BC rows
      int j = idx - 65536; int r = j >> 8, k = j & 255;
      b_xp2[j] = f2bf(w_xp[(8 + r) * 256 + k]);
    } else if (idx < 65536 + 8192 + 65536) {       // combo rows
      int j = idx - (65536 + 8192); int d = j >> 8, k = j & 255;
      float acc = 0.f;
      #pragma unroll
      for (int r = 0; r < 8; ++r) acc += w_dt[d * 8 + r] * w_xp[r * 256 + k];
      b_xp2[8192 + j] = f2bf(acc);
    } else if (idx < 65536 + 8192 + 65536 + 8192) {  // zero pad rows
      b_xp2[73728 + (idx - 139264)] = 0;
    } else if (idx < 180224) {
      int j = idx - 147456;
      b_out[j] = f2bf(w_out[j]);
    }
  } else {
    __shared__ float red[64][8];
    __shared__ float stat[64][2];
    __shared__ ushort T[64][136];
    const int t = threadIdx.x;
    const int l = t & 63, q = t >> 6;
    const int l0 = (blockIdx.x - 704) * 64;
    float vals[32];
    float sum = 0.f, sq = 0.f;
    #pragma unroll 8
    for (int cc = 0; cc < 32; ++cc) {
      float v = x[(size_t)(q * 32 + cc) * LQ + l0 + l];
      vals[cc] = v;
      sum += v; sq += v * v;
    }
    red[l][q] = sum; red[l][4 + q] = sq;
    __syncthreads();
    if (t < 64) {
      float s  = red[t][0] + red[t][1] + red[t][2] + red[t][3];
      float s2 = red[t][4] + red[t][5] + red[t][6] + red[t][7];
      float mu = s * (1.f / 128.f);
      float var = s2 * (1.f / 128.f) - mu * mu;
      stat[t][0] = mu; stat[t][1] = rsqrtf(var + 1e-5f);
    }
    __syncthreads();
    float mu = stat[l][0], rs = stat[l][1];
    #pragma unroll 8
    for (int cc = 0; cc < 32; ++cc) {
      int c = q * 32 + cc;
      T[l][c] = f2bf((vals[cc] - mu) * rs * lnw[c] + lnb[c]);
    }
    __syncthreads();
    int row = t >> 2, seg = t & 3;
    #pragma unroll
    for (int j = 0; j < 4; ++j) {
      short8v v = *(const short8v*)&T[row][seg * 32 + j * 8];
      *(short8v*)&tn[(size_t)(l0 + row) * 128 + seg * 32 + j * 8] = v;
    }
  }
}

// ---------------- in_proj GEMM + fused conv/SiLU (xs half) / z store ----------------
// Grid (NB, 8). y<4: conv epilogue -> xa (L,256). y>=4: store z -> zt (L,256).
__global__ __launch_bounds__(256) void gemm_in_conv(
    const ushort* __restrict__ Wb,     // 512x128 bf16
    const ushort* __restrict__ Act,    // tn (L,128) bf16
    const float* __restrict__ cw, const float* __restrict__ cb,
    ushort* __restrict__ xa, ushort* __restrict__ zt) {
  constexpr int K = 128, KO = 16;
  __shared__ ushort As[64 * K];
  __shared__ ushort Bs[2][128 * 64];
  __shared__ __align__(16) ushort bnd[3 * 64];
  const int tid = threadIdx.x;
  const int l0 = blockIdx.x * 128;
  const int my = blockIdx.y;
  const int m0 = my * 64;
  const bool isconv = (my < 4);
  // stage A (weights) once, swizzled
  #pragma unroll
  for (int i = 0; i < 4; ++i) {
    int cid = i * 256 + tid;
    int m = cid / KO, oct = cid % KO;
    short8v v = *(const short8v*)&Wb[(size_t)(m0 + m) * K + oct * 8];
    *(short8v*)&As[m * K + ((oct ^ (m & 7)) * 8)] = v;
  }
  // issue B k0=0 via gl_lds (linear dest, inverse-swizzled source)
  #pragma unroll
  for (int i = 0; i < 4; ++i) {
    int cid = i * 256 + tid;
    int l = cid >> 3, oct = (cid & 7) ^ (l & 7);
    gl_lds16(&Act[(size_t)(l0 + l) * 128 + oct * 8], &Bs[0][cid * 8]);
  }
  // boundary xs rows (l0-3..l0-1) via VALU dot (hidden under gl_lds latency)
  if (isconv && tid < 192) {
    int r = tid >> 6, m = tid & 63;
    int lg = l0 - 3 + r;
    float acc = 0.f;
    if (lg >= 0) {
      const ushort* wr = &Wb[(size_t)(m0 + m) * K];
      const ushort* tr = &Act[(size_t)lg * 128];
      for (int k = 0; k < 128; k += 8) {
        short8v wv = *(const short8v*)&wr[k];
        short8v tv = *(const short8v*)&tr[k];
        #pragma unroll
        for (int j = 0; j < 8; ++j)
          acc = fmaf(bf2f((ushort)wv[j]), bf2f((ushort)tv[j]), acc);
      }
    }
    bnd[r * 64 + m] = f2bf(acc);
  }
  float4v acc[4][2];
  #pragma unroll
  for (int a = 0; a < 4; ++a)
    #pragma unroll
    for (int b = 0; b < 2; ++b) acc[a][b] = (float4v)0.f;
  const int w = tid >> 6, lane = tid & 63;
  const int r = lane & 15, g = lane >> 4;
  int buf = 0;
  __syncthreads();
  for (int k0 = 0; k0 < K; k0 += 64) {
    if (k0 + 64 < K) {
      #pragma unroll
      for (int i = 0; i < 4; ++i) {
        int cid = i * 256 + tid;
        int l = cid >> 3, oct = (cid & 7) ^ (l & 7);
        gl_lds16(&Act[(size_t)(l0 + l) * 128 + (k0 + 64) + oct * 8],
                 &Bs[buf ^ 1][cid * 8]);
      }
    }
    const ushort* bp = Bs[buf];
    #pragma unroll
    for (int kk = 0; kk < 2; ++kk) {
      short8v af[4], bfv[2];
      int ko = (k0 >> 3) + kk * 4 + g;
      #pragma unroll
      for (int mf = 0; mf < 4; ++mf) {
        int row = mf * 16 + r;
        af[mf] = *(const short8v*)&As[row * K + ((ko ^ (row & 7)) * 8)];
      }
      int kob = kk * 4 + g;
      #pragma unroll
      for (int nf = 0; nf < 2; ++nf) {
        int row = w * 32 + nf * 16 + r;
        bfv[nf] = *(const short8v*)&bp[row * 64 + ((kob ^ (row & 7)) * 8)];
      }
      #pragma unroll
      for (int mf = 0; mf < 4; ++mf)
        #pragma unroll
        for (int nf = 0; nf < 2; ++nf)
          acc[mf][nf] = __builtin_amdgcn_mfma_f32_16x16x32_bf16(af[mf], bfv[nf], acc[mf][nf], 0, 0, 0);
    }
    __syncthreads();
    buf ^= 1;
  }
  // dump [l][m] bf16 tile into Bs[0] (swizzled)
  #pragma unroll
  for (int mf = 0; mf < 4; ++mf) {
    #pragma unroll
    for (int nf = 0; nf < 2; ++nf) {
      int l = w * 32 + nf * 16 + r;
      int m = mf * 16 + g * 4;
      ushort u0 = f2bf(acc[mf][nf][0]), u1 = f2bf(acc[mf][nf][1]);
      ushort u2 = f2bf(acc[mf][nf][2]), u3 = f2bf(acc[mf][nf][3]);
      uint2 pk = make_uint2((uint)u0 | ((uint)u1 << 16), (uint)u2 | ((uint)u3 << 16));
      int oct = (m >> 3) ^ (l & 7);
      *(uint2*)&Bs[0][l * 64 + oct * 8 + (g & 1) * 4] = pk;
    }
  }
  __syncthreads();
  if (isconv) {
    // conv weights for this thread's fixed m-octet
    const int oct_ = tid & 7;
    const int dbase = m0 + oct_ * 8;
    float w0[8], w1[8], w2[8], w3[8], bb8[8];
    #pragma unroll
    for (int j = 0; j < 8; ++j) {
      float4 wv = *(const float4*)&cw[(dbase + j) * 4];
      w0[j] = wv.x; w1[j] = wv.y; w2[j] = wv.z; w3[j] = wv.w;
      bb8[j] = cb[dbase + j];
    }
    #pragma unroll
    for (int i = 0; i < 4; ++i) {
      int cid = i * 256 + tid;
      int row = cid >> 3, oct = cid & 7;
      short8v s[4];
      #pragma unroll
      for (int t = 0; t < 4; ++t) {
        int rr = row - 3 + t;
        if (rr >= 0)
          s[t] = *(const short8v*)&Bs[0][rr * 64 + ((oct ^ (rr & 7)) * 8)];
        else
          s[t] = *(const short8v*)&bnd[(rr + 3) * 64 + oct * 8];
      }
      short8v ov;
      #pragma unroll
      for (int j = 0; j < 8; ++j) {
        float a = bb8[j] + w0[j] * bf2f((ushort)s[0][j]) + w1[j] * bf2f((ushort)s[1][j])
                         + w2[j] * bf2f((ushort)s[2][j]) + w3[j] * bf2f((ushort)s[3][j]);
        ov[j] = (short)f2bf(a / (1.f + __expf(-a)));
      }
      *(short8v*)&xa[(size_t)(l0 + row) * 256 + m0 + oct * 8] = ov;
    }
  } else {
    #pragma unroll
    for (int i = 0; i < 4; ++i) {
      int cid = i * 256 + tid;
      int row = cid >> 3, oct = cid & 7;
      short8v v = *(const short8v*)&Bs[0][row * 64 + ((oct ^ (row & 7)) * 8)];
      *(short8v*)&zt[(size_t)(l0 + row) * 256 + (m0 - 256) + oct * 8] = v;
    }
  }
}

// ---------------- MFMA GEMM (token-major out): 128l x 64m tile, gl_lds dbuf B ----------------
template<int K, int MV, int BSTR, int CSTR>
__global__ __launch_bounds__(256) void gemm_tok(
    const ushort* __restrict__ Wb,
    const ushort* __restrict__ Act,
    ushort* __restrict__ Out) {
  constexpr int KO = K / 8;
  __shared__ ushort As[64 * K];
  __shared__ ushort Bs[2][128 * 64];
  const int tid = threadIdx.x;
  const int l0 = blockIdx.x * 128;
  const int m0 = blockIdx.y * 64;
  #pragma unroll
  for (int i = 0; i < (64 * KO) / 256; ++i) {
    int cid = i * 256 + tid;
    int m = cid / KO, oct = cid % KO;
    short8v v = *(const short8v*)&Wb[(size_t)(m0 + m) * K + oct * 8];
    *(short8v*)&As[m * K + ((oct ^ (m & 7)) * 8)] = v;
  }
  #pragma unroll
  for (int i = 0; i < 4; ++i) {
    int cid = i * 256 + tid;
    int l = cid >> 3, oct = (cid & 7) ^ (l & 7);
    gl_lds16(&Act[(size_t)(l0 + l) * BSTR + oct * 8], &Bs[0][cid * 8]);
  }
  float4v acc[4][2];
  #pragma unroll
  for (int a = 0; a < 4; ++a)
    #pragma unroll
    for (int b = 0; b < 2; ++b) acc[a][b] = (float4v)0.f;
  const int w = tid >> 6, lane = tid & 63;
  const int r = lane & 15, g = lane >> 4;
  int buf = 0;
  __syncthreads();
  for (int k0 = 0; k0 < K; k0 += 64) {
    if (k0 + 64 < K) {
      #pragma unroll
      for (int i = 0; i < 4; ++i) {
        int cid = i * 256 + tid;
        int l = cid >> 3, oct = (cid & 7) ^ (l & 7);
        gl_lds16(&Act[(size_t)(l0 + l) * BSTR + (k0 + 64) + oct * 8],
                 &Bs[buf ^ 1][cid * 8]);
      }
    }
    const ushort* bp = Bs[buf];
    #pragma unroll
    for (int kk = 0; kk < 2; ++kk) {
      short8v af[4], bfv[2];
      int ko = (k0 >> 3) + kk * 4 + g;
      #pragma unroll
      for (int mf = 0; mf < 4; ++mf) {
        int row = mf * 16 + r;
        af[mf] = *(const short8v*)&As[row * K + ((ko ^ (row & 7)) * 8)];
      }
      int kob = kk * 4 + g;
      #pragma unroll
      for (int nf = 0; nf < 2; ++nf) {
        int row = w * 32 + nf * 16 + r;
        bfv[nf] = *(const short8v*)&bp[row * 64 + ((kob ^ (row & 7)) * 8)];
      }
      #pragma unroll
      for (int mf = 0; mf < 4; ++mf)
        #pragma unroll
        for (int nf = 0; nf < 2; ++nf)
          acc[mf][nf] = __builtin_amdgcn_mfma_f32_16x16x32_bf16(af[mf], bfv[nf], acc[mf][nf], 0, 0, 0);
    }
    __syncthreads();
    buf ^= 1;
  }
  #pragma unroll
  for (int mf = 0; mf < 4; ++mf) {
    #pragma unroll
    for (int nf = 0; nf < 2; ++nf) {
      int l = w * 32 + nf * 16 + r;
      int m = mf * 16 + g * 4;
      ushort u0 = f2bf(acc[mf][nf][0]), u1 = f2bf(acc[mf][nf][1]);
      ushort u2 = f2bf(acc[mf][nf][2]), u3 = f2bf(acc[mf][nf][3]);
      uint2 pk = make_uint2((uint)u0 | ((uint)u1 << 16), (uint)u2 | ((uint)u3 << 16));
      int oct = (m >> 3) ^ (l & 7);
      *(uint2*)&Bs[0][l * 64 + oct * 8 + (g & 1) * 4] = pk;
    }
  }
  __syncthreads();
  #pragma unroll
  for (int i = 0; i < 4; ++i) {
    int cid = i * 256 + tid;
    int row = cid >> 3, oct = cid & 7;
    if (oct * 8 < MV) {
      short8v v = *(const short8v*)&Bs[0][row * 64 + ((oct ^ (row & 7)) * 8)];
      *(short8v*)&Out[(size_t)(l0 + row) * CSTR + m0 + oct * 8] = v;
    }
  }
}

// ---------------- out_proj GEMM (swapped operands) + fp32 residual ----------------
__global__ __launch_bounds__(256) void gemm_out_k(
    const ushort* __restrict__ Wb,
    const ushort* __restrict__ Yg,    // 16 slabs of (L,16) bf16
    const float* __restrict__ X,
    float* __restrict__ Out) {
  __shared__ ushort Ay[2][128 * 64];
  __shared__ ushort Bw[64 * 256];
  const int tid = threadIdx.x;
  const int l0 = blockIdx.x * 128;
  const int c0 = blockIdx.y * 64;
  const int w = tid >> 6, lane = tid & 63;
  const int r = lane & 15, g = lane >> 4;
  #pragma unroll
  for (int i = 0; i < 8; ++i) {
    int cid = i * 256 + tid;
    int row = cid >> 5, oct = cid & 31;
    short8v vb = *(const short8v*)&Wb[(size_t)(c0 + row) * 256 + oct * 8];
    *(short8v*)&Bw[row * 256 + ((oct ^ (row & 7)) * 8)] = vb;
  }
  #pragma unroll
  for (int i = 0; i < 4; ++i) {
    int cid = i * 256 + tid;
    int row = cid >> 3, oct = (cid & 7) ^ (row & 7);
    gl_lds16(&Yg[((size_t)(oct >> 1) * LQ + l0 + row) * 16 + (oct & 1) * 8],
             &Ay[0][cid * 8]);
  }
  float4v acc[2][4];
  #pragma unroll
  for (int a = 0; a < 2; ++a)
    #pragma unroll
    for (int b = 0; b < 4; ++b) acc[a][b] = (float4v)0.f;
  int buf = 0;
  __syncthreads();
  for (int k0 = 0; k0 < 256; k0 += 64) {
    if (k0 + 64 < 256) {
      int ks = (k0 + 64) >> 4;
      #pragma unroll
      for (int i = 0; i < 4; ++i) {
        int cid = i * 256 + tid;
        int row = cid >> 3, oct = (cid & 7) ^ (row & 7);
        gl_lds16(&Yg[((size_t)(ks + (oct >> 1)) * LQ + l0 + row) * 16 + (oct & 1) * 8],
                 &Ay[buf ^ 1][cid * 8]);
      }
    }
    const ushort* ap = Ay[buf];
    #pragma unroll
    for (int kk = 0; kk < 2; ++kk) {
      int kob = kk * 4 + g;
      int ko = (k0 >> 3) + kob;
      short8v af[2], bfv[4];
      #pragma unroll
      for (int mf = 0; mf < 2; ++mf) {
        int row = w * 32 + mf * 16 + r;
        af[mf] = *(const short8v*)&ap[row * 64 + ((kob ^ (row & 7)) * 8)];
      }
      #pragma unroll
      for (int nf = 0; nf < 4; ++nf) {
        int row = nf * 16 + r;
        bfv[nf] = *(const short8v*)&Bw[row * 256 + ((ko ^ (row & 7)) * 8)];
      }
      #pragma unroll
      for (int mf = 0; mf < 2; ++mf)
        #pragma unroll
        for (int nf = 0; nf < 4; ++nf)
          acc[mf][nf] = __builtin_amdgcn_mfma_f32_16x16x32_bf16(af[mf], bfv[nf], acc[mf][nf], 0, 0, 0);
    }
    __syncthreads();
    buf ^= 1;
  }
  #pragma unroll
  for (int mf = 0; mf < 2; ++mf) {
    #pragma unroll
    for (int nf = 0; nf < 4; ++nf) {
      int c = c0 + nf * 16 + r;
      int l = l0 + w * 32 + mf * 16 + g * 4;
      size_t off = (size_t)c * LQ + l;
      float4 rv = *(const float4*)&X[off];
      float4 o = make_float4(acc[mf][nf][0] + rv.x, acc[mf][nf][1] + rv.y,
                             acc[mf][nf][2] + rv.z, acc[mf][nf][3] + rv.w);
      *(float4*)&Out[off] = o;
    }
  }
}

// ---------------- scan pass 1: local scan, 4 states/thread, CH=64 ----------------
__global__ __launch_bounds__(256) void scan1(const ushort* __restrict__ xdbl,
    const ushort* __restrict__ xa, const float* __restrict__ bias,
    const float* __restrict__ A_log, float* __restrict__ Stot, float* __restrict__ Hc,
    ushort* __restrict__ yloc) {
  __shared__ uint  duL[64 * 64];    // [i][d] (dt lo | dt*xa hi)        16 KB
  __shared__ float bcL[64 * 32];    // [i][B0..15 C16..31] fp32          8 KB
  __shared__ ushort ylds[64 * 72];  // [i][d] y bf16 (pad 72)          9.2 KB
  const int tid = threadIdx.x;
  const int c = blockIdx.x, dg = blockIdx.y;
  const int dloc = tid >> 2, sq = tid & 3;
  const int d = dg * 64 + dloc;
  const int lb = c * CH;
  float4v A, h;
  #pragma unroll
  for (int k = 0; k < 4; ++k) {
    A[k] = -__expf(A_log[d * 16 + sq * 4 + k]);
    h[k] = 0.f;
  }
  float S = 0.f;
  {   // stage (dt, dt*xa)
    const int doff = dg * 64 + sq * 16;
    const ushort* xr = xdbl + (size_t)(lb + dloc) * 320 + 32 + doff;
    const ushort* xar = xa + (size_t)(lb + dloc) * 256 + doff;
    short8v d0 = *(const short8v*)xr;
    short8v d1 = *(const short8v*)(xr + 8);
    short8v x0 = *(const short8v*)xar;
    short8v x1 = *(const short8v*)(xar + 8);
    uint pk[16];
    #pragma unroll
    for (int j = 0; j < 8; ++j) {
      float sp = softplus_f(bf2f((ushort)d0[j]) + bias[doff + j]);
      pk[j] = (uint)f2bf(sp) | ((uint)f2bf(sp * bf2f((ushort)x0[j])) << 16);
      float sp2 = softplus_f(bf2f((ushort)d1[j]) + bias[doff + 8 + j]);
      pk[8 + j] = (uint)f2bf(sp2) | ((uint)f2bf(sp2 * bf2f((ushort)x1[j])) << 16);
    }
    uint4* dst = (uint4*)&duL[dloc * 64 + sq * 16];
    #pragma unroll
    for (int j = 0; j < 4; ++j)
      dst[j] = make_uint4(pk[4 * j], pk[4 * j + 1], pk[4 * j + 2], pk[4 * j + 3]);
  }
  if (tid < 128) {  // stage B, C as fp32
    int row = tid >> 1, half = tid & 1;
    const ushort* xr = xdbl + (size_t)(lb + row) * 320;
    short8v bv = *(const short8v*)(xr + half * 8);
    short8v cv = *(const short8v*)(xr + 16 + half * 8);
    float* bd = &bcL[row * 32 + half * 8];
    float* cd = &bcL[row * 32 + 16 + half * 8];
    #pragma unroll
    for (int j = 0; j < 8; ++j) {
      bd[j] = bf2f((ushort)bv[j]);
      cd[j] = bf2f((ushort)cv[j]);
    }
  }
  __syncthreads();
  #pragma unroll 4
  for (int i = 0; i < CH; ++i) {
    uint pv = duL[i * 64 + dloc];
    float dtv = __uint_as_float(pv << 16);
    float dxv = __uint_as_float(pv & 0xffff0000u);
    S += dtv;
    float4v Bv = *(const float4v*)&bcL[i * 32 + sq * 4];
    float4v Cv = *(const float4v*)&bcL[i * 32 + 16 + sq * 4];
    float t = 0.f;
    #pragma unroll
    for (int k = 0; k < 4; ++k) {
      float a = __expf(dtv * A[k]);
      h[k] = fmaf(a, h[k], dxv * Bv[k]);
      t = fmaf(h[k], Cv[k], t);
    }
    t = quad_reduce(t);
    if (sq == 0) ylds[i * 72 + dloc] = f2bf(t);
  }
  __syncthreads();
  {   // flush y -> slabs
    int slab = tid >> 6, row = tid & 63;
    short8v v0 = *(const short8v*)&ylds[row * 72 + slab * 16];
    short8v v1 = *(const short8v*)&ylds[row * 72 + slab * 16 + 8];
    ushort* dst = &yloc[((size_t)(dg * 4 + slab) * LQ + lb + row) * 16];
    *(short8v*)dst = v0;
    *(short8v*)(dst + 8) = v1;
  }
  *(float4*)&Hc[(size_t)(c * 256 + d) * 16 + sq * 4] = make_float4(h[0], h[1], h[2], h[3]);
  if (sq == 0) Stot[c * 256 + d] = S;
}

// ---------------- scan combine: serial over chunks, batch-8 load pipeline ----------------
__global__ __launch_bounds__(256) void scan_combine(const float* __restrict__ Stot,
    const float* __restrict__ Hc, const float* __restrict__ A_log,
    float* __restrict__ Hin) {
  int t = blockIdx.x * 256 + threadIdx.x;   // d*16 + s
  int d = t >> 4;
  float A = -__expf(A_log[t]);
  float h = 0.f;
  for (int cb = 0; cb < NC; cb += 8) {
    float a[8], b[8];
    #pragma unroll
    for (int j = 0; j < 8; ++j) {          // independent loads, issue together
      a[j] = Stot[(cb + j) * 256 + d];
      b[j] = Hc[(size_t)(cb + j) * 4096 + t];
    }
    #pragma unroll
    for (int j = 0; j < 8; ++j) {          // dependent chain
      Hin[(size_t)(cb + j) * 4096 + t] = h;
      h = fmaf(__expf(A * a[j]), h, b[j]);
    }
  }
}

// ---------------- scan pass 2: parallel correction + gate, 4 states/thread, CH=64 ----------------
__global__ __launch_bounds__(256) void scan2(const ushort* __restrict__ xdbl,
    const ushort* __restrict__ xa, const ushort* __restrict__ zt,
    const float* __restrict__ bias, const float* __restrict__ A_log,
    const float* __restrict__ Dp, const float* __restrict__ Hin,
    ushort* __restrict__ yg) {
  __shared__ uint  dtp[32 * 64];    // [i2][d] (dt even lo | odd hi)     8 KB
  __shared__ float cL[64 * 16];     // [i][C0..15] fp32                  4 KB
  __shared__ float corr[64 * 68];   // [i][d] fp32 (pad 68)           17.4 KB
  const int tid = threadIdx.x;
  const int c = blockIdx.x, dg = blockIdx.y;
  const int dloc = tid >> 2, sq = tid & 3;
  const int d = dg * 64 + dloc;
  const int lb = c * CH;
  float4v A, hin;
  #pragma unroll
  for (int k = 0; k < 4; ++k) A[k] = -__expf(A_log[d * 16 + sq * 4 + k]);
  {
    float4 hv = *(const float4*)&Hin[(size_t)(c * 256 + d) * 16 + sq * 4];
    hin[0] = hv.x; hin[1] = hv.y; hin[2] = hv.z; hin[3] = hv.w;
  }
  float S = 0.f;
  {   // stage dt pairs
    int rp = tid >> 3, seg = tid & 7;
    const int doff = dg * 64 + seg * 8;
    const ushort* xr0 = xdbl + (size_t)(lb + 2 * rp) * 320 + 32 + doff;
    short8v e0 = *(const short8v*)xr0;
    short8v e1 = *(const short8v*)(xr0 + 320);
    uint pk[8];
    #pragma unroll
    for (int j = 0; j < 8; ++j) {
      float spe = softplus_f(bf2f((ushort)e0[j]) + bias[doff + j]);
      float spo = softplus_f(bf2f((ushort)e1[j]) + bias[doff + j]);
      pk[j] = (uint)f2bf(spe) | ((uint)f2bf(spo) << 16);
    }
    uint4* dst = (uint4*)&dtp[rp * 64 + seg * 8];
    dst[0] = make_uint4(pk[0], pk[1], pk[2], pk[3]);
    dst[1] = make_uint4(pk[4], pk[5], pk[6], pk[7]);
  }
  if (tid < 128) {  // stage C fp32
    int row = tid >> 1, half = tid & 1;
    short8v cv = *(const short8v*)(xdbl + (size_t)(lb + row) * 320 + 16 + half * 8);
    float* cd = &cL[row * 16 + half * 8];
    #pragma unroll
    for (int j = 0; j < 8; ++j) cd[j] = bf2f((ushort)cv[j]);
  }
  __syncthreads();
  #pragma unroll 2
  for (int i2 = 0; i2 < CH / 2; ++i2) {
    uint pv = dtp[i2 * 64 + dloc];
    #pragma unroll
    for (int par = 0; par < 2; ++par) {
      float dtv = (par == 0) ? __uint_as_float(pv << 16)
                             : __uint_as_float(pv & 0xffff0000u);
      S += dtv;
      int i = i2 * 2 + par;
      float4v Cv = *(const float4v*)&cL[i * 16 + sq * 4];
      float t = 0.f;
      #pragma unroll
      for (int k = 0; k < 4; ++k)
        t = fmaf(__expf(A[k] * S), hin[k] * Cv[k], t);
      t = quad_reduce(t);
      if (sq == 0) corr[i * 68 + dloc] = t;
    }
  }
  __syncthreads();
  {   // flush: y = (yloc + corr + xa*D) * silu(z)
    int slab = tid >> 6, row = tid & 63;
    const int doff = dg * 64 + slab * 16;
    size_t sl = ((size_t)(dg * 4 + slab) * LQ + lb + row) * 16;
    short8v y0 = *(const short8v*)&yg[sl];
    short8v y1 = *(const short8v*)&yg[sl + 8];
    const ushort* xav = xa + (size_t)(lb + row) * 256 + doff;
    short8v x0 = *(const short8v*)xav;
    short8v x1 = *(const short8v*)(xav + 8);
    const ushort* zvp = zt + (size_t)(lb + row) * 256 + doff;
    short8v z0 = *(const short8v*)zvp;
    short8v z1 = *(const short8v*)(zvp + 8);
    float4 c0 = *(const float4*)&corr[row * 68 + slab * 16];
    float4 c1 = *(const float4*)&corr[row * 68 + slab * 16 + 4];
    float4 c2 = *(const float4*)&corr[row * 68 + slab * 16 + 8];
    float4 c3 = *(const float4*)&corr[row * 68 + slab * 16 + 12];
    float cr[16] = {c0.x, c0.y, c0.z, c0.w, c1.x, c1.y, c1.z, c1.w,
                    c2.x, c2.y, c2.z, c2.w, c3.x, c3.y, c3.z, c3.w};
    short8v o0, o1;
    #pragma unroll
    for (int j = 0; j < 8; ++j) {
      float v0 = bf2f((ushort)y0[j]) + cr[j] + bf2f((ushort)x0[j]) * Dp[doff + j];
      float zf0 = bf2f((ushort)z0[j]);
      o0[j] = (short)f2bf(v0 * (zf0 / (1.f + __expf(-zf0))));
      float v1 = bf2f((ushort)y1[j]) + cr[8 + j] + bf2f((ushort)x1[j]) * Dp[doff + 8 + j];
      float zf1 = bf2f((ushort)z1[j]);
      o1[j] = (short)f2bf(v1 * (zf1 / (1.f + __expf(-zf1))));
    }
    *(short8v*)&yg[sl] = o0;
    *(short8v*)&yg[sl + 8] = o1;
  }
}

extern "C" void kernel_launch(void* const* d_in, const int* in_sizes, int n_in,
                              void* d_out, int out_size, void* d_ws, size_t ws_size,
                              hipStream_t stream) {
  const float* x         = (const float*)d_in[0];
  const float* ln_w      = (const float*)d_in[1];
  const float* ln_b      = (const float*)d_in[2];
  const float* in_proj_w = (const float*)d_in[3];
  const float* conv_w    = (const float*)d_in[4];
  const float* conv_b    = (const float*)d_in[5];
  const float* x_proj_w  = (const float*)d_in[6];
  const float* dt_proj_w = (const float*)d_in[7];
  const float* dt_proj_b = (const float*)d_in[8];
  const float* A_log     = (const float*)d_in[9];
  const float* D_param   = (const float*)d_in[10];
  const float* out_proj_w= (const float*)d_in[11];
  float* out = (float*)d_out;

  char* ws = (char*)d_ws;
  ushort* wbf_in  = (ushort*)(ws + 0);           // 512x128
  ushort* wbf_xp2 = (ushort*)(ws + 131072);      // 320x256
  ushort* wbf_out = (ushort*)(ws + 294912);      // 128x256
  float*  Hin     = (float*)(ws + 360448);       // 216x4096
  float*  Hc      = (float*)(ws + 3899392);      // 216x4096
  float*  Stot    = (float*)(ws + 7438336);      // 216x256
  ushort* tn_t    = (ushort*)(ws + 7659520);     // (L,128)
  ushort* zt      = (ushort*)(ws + 11198464);    // (L,256) gate z
  ushort* xa_t    = (ushort*)(ws + 18276352);    // (L,256)
  ushort* xdbl_t  = (ushort*)(ws + 25354240);    // (L,320): B 0..15, C 16..31, dt_lin 32..287
  ushort* yg_t    = (ushort*)(ws + 34201600);    // 16 slabs (L,16)

  prep_ln<<<920, 256, 0, stream>>>(in_proj_w, x_proj_w, dt_proj_w, out_proj_w,
                                   x, ln_w, ln_b, wbf_in, wbf_xp2, wbf_out, tn_t);
  gemm_in_conv<<<dim3(NB, 8), 256, 0, stream>>>(wbf_in, tn_t, conv_w, conv_b, xa_t, zt);
  gemm_tok<256, 64, 256, 320><<<dim3(NB, 5), 256, 0, stream>>>(wbf_xp2, xa_t, xdbl_t);
  scan1<<<dim3(NC, 4), 256, 0, stream>>>(xdbl_t, xa_t, dt_proj_b, A_log, Stot, Hc, yg_t);
  scan_combine<<<16, 256, 0, stream>>>(Stot, Hc, A_log, Hin);
  scan2<<<dim3(NC, 4), 256, 0, stream>>>(xdbl_t, xa_t, zt, dt_proj_b, A_log,
                                         D_param, Hin, yg_t);
  gemm_out_k<<<dim3(NB, 2), 256, 0, stream>>>(wbf_out, yg_t, x, out);
}

// Round 13
// 200.038 us; speedup vs baseline: 2.4391x; 1.0149x over previous
//
#include <hip/hip_runtime.h>
#include <hip/hip_bf16.h>
#include <math.h>

// MambaBlock3D: B=1, C=128, L=24^3=13824, D_INNER=256, D_STATE=16, D_CONV=4, DT_RANK=8
// Token-major bf16 activations, MFMA GEMMs (per-kstep dbuf A+B, 48KB LDS), fp32 scan.

constexpr int LQ = 13824;
constexpr int NC = 216;     // scan chunks (CH=64)
constexpr int CH = 64;      // chunk length
constexpr int NB = 108;     // 128-l GEMM tiles
constexpr int DI = 256;
constexpr int DS = 16;

typedef __attribute__((ext_vector_type(8))) short short8v;   // 8 bf16 = 4 VGPR
typedef __attribute__((ext_vector_type(4))) float float4v;

__device__ __forceinline__ ushort f2bf(float f) {
  uint u = __float_as_uint(f);
  u += 0x7FFFu + ((u >> 16) & 1u);          // round-to-nearest-even
  return (ushort)(u >> 16);
}
__device__ __forceinline__ float bf2f(ushort u) {
  return __uint_as_float(((uint)u) << 16);
}
// async global->LDS, 16 bytes per lane; dest must be linear (base + lane*16)
__device__ __forceinline__ void gl_lds16(const ushort* g, ushort* l) {
  __builtin_amdgcn_global_load_lds(
      (const __attribute__((address_space(1))) void*)g,
      (__attribute__((address_space(3))) void*)l, 16, 0, 0);
}

template<int CTRL>
__device__ __forceinline__ float dpp_add(float x) {
  int y = __builtin_amdgcn_update_dpp(0, __float_as_int(x), CTRL, 0xF, 0xF, true);
  return x + __int_as_float(y);
}
// quad butterfly: all 4 lanes of each quad get the quad sum
__device__ __forceinline__ float quad_reduce(float t) {
  t = dpp_add<0xB1>(t);    // quad_perm xor1
  t = dpp_add<0x4E>(t);    // quad_perm xor2
  return t;
}
__device__ __forceinline__ float softplus_f(float x) {
  return (x > 20.f) ? x : log1pf(__expf(x));
}

// ---------------- prep (blocks 0..703) + LayerNorm (blocks 704..919) ----------------
// wbf_xp2 (320 x 256): rows 0..15 = B rows, 16..31 = C rows, 32..287 = dt_lin combo, 288..319 = 0.
__global__ __launch_bounds__(256) void prep_ln(const float* __restrict__ w_in,
    const float* __restrict__ w_xp, const float* __restrict__ w_dt,
    const float* __restrict__ w_out,
    const float* __restrict__ x, const float* __restrict__ lnw,
    const float* __restrict__ lnb,
    ushort* __restrict__ b_in, ushort* __restrict__ b_xp2, ushort* __restrict__ b_out,
    ushort* __restrict__ tn) {
  if (blockIdx.x < 704) {
    int idx = blockIdx.x * 256 + threadIdx.x;
    if (idx < 65536) {
      b_in[idx] = f2bf(w_in[idx]);
    } else if (idx < 65536 + 8192) {               // BC rows
      int j = idx - 65536; int r = j >> 8, k = j & 255;
      b_xp2[j] = f2bf(w_xp[(8 + r) * 256 + k]);
    } else if (idx < 65536 + 8192 + 65536) {       // combo rows
      int j = idx - (65536 + 8192); int d = j >> 8, k = j & 255;
      float acc = 0.f;
      #pragma unroll
      for (int r = 0; r < 8; ++r) acc += w_dt[d * 8 + r] * w_xp[r * 256 + k];
      b_xp2[8192 + j] = f2bf(acc);
    } else if (idx < 65536 + 8192 + 65536 + 8192) {  // zero pad rows
      b_xp2[73728 + (idx - 139264)] = 0;
    } else if (idx < 180224) {
      int j = idx - 147456;
      b_out[j] = f2bf(w_out[j]);
    }
  } else {
    __shared__ float red[64][8];
    __shared__ float stat[64][2];
    __shared__ ushort T[64][136];
    const int t = threadIdx.x;
    const int l = t & 63, q = t >> 6;
    const int l0 = (blockIdx.x - 704) * 64;
    float vals[32];
    float sum = 0.f, sq = 0.f;
    #pragma unroll 8
    for (int cc = 0; cc < 32; ++cc) {
      float v = x[(size_t)(q * 32 + cc) * LQ + l0 + l];
      vals[cc] = v;
      sum += v; sq += v * v;
    }
    red[l][q] = sum; red[l][4 + q] = sq;
    __syncthreads();
    if (t < 64) {
      float s  = red[t][0] + red[t][1] + red[t][2] + red[t][3];
      float s2 = red[t][4] + red[t][5] + red[t][6] + red[t][7];
      float mu = s * (1.f / 128.f);
      float var = s2 * (1.f / 128.f) - mu * mu;
      stat[t][0] = mu; stat[t][1] = rsqrtf(var + 1e-5f);
    }
    __syncthreads();
    float mu = stat[l][0], rs = stat[l][1];
    #pragma unroll 8
    for (int cc = 0; cc < 32; ++cc) {
      int c = q * 32 + cc;
      T[l][c] = f2bf((vals[cc] - mu) * rs * lnw[c] + lnb[c]);
    }
    __syncthreads();
    int row = t >> 2, seg = t & 3;
    #pragma unroll
    for (int j = 0; j < 4; ++j) {
      short8v v = *(const short8v*)&T[row][seg * 32 + j * 8];
      *(short8v*)&tn[(size_t)(l0 + row) * 128 + seg * 32 + j * 8] = v;
    }
  }
}

// ---------------- in_proj GEMM + fused conv/SiLU (xs half) / z store ----------------
// Grid (NB, 8). y<4: conv epilogue -> xa (L,256). y>=4: store z -> zt (L,256).
__global__ __launch_bounds__(256) void gemm_in_conv(
    const ushort* __restrict__ Wb,     // 512x128 bf16
    const ushort* __restrict__ Act,    // tn (L,128) bf16
    const float* __restrict__ cw, const float* __restrict__ cb,
    ushort* __restrict__ xa, ushort* __restrict__ zt) {
  constexpr int K = 128, KO = 16;
  __shared__ ushort As[64 * K];
  __shared__ ushort Bs[2][128 * 64];
  __shared__ __align__(16) ushort bnd[3 * 64];
  const int tid = threadIdx.x;
  const int l0 = blockIdx.x * 128;
  const int my = blockIdx.y;
  const int m0 = my * 64;
  const bool isconv = (my < 4);
  // stage A (weights) once, swizzled
  #pragma unroll
  for (int i = 0; i < 4; ++i) {
    int cid = i * 256 + tid;
    int m = cid / KO, oct = cid % KO;
    short8v v = *(const short8v*)&Wb[(size_t)(m0 + m) * K + oct * 8];
    *(short8v*)&As[m * K + ((oct ^ (m & 7)) * 8)] = v;
  }
  // issue B k0=0 via gl_lds (linear dest, inverse-swizzled source)
  #pragma unroll
  for (int i = 0; i < 4; ++i) {
    int cid = i * 256 + tid;
    int l = cid >> 3, oct = (cid & 7) ^ (l & 7);
    gl_lds16(&Act[(size_t)(l0 + l) * 128 + oct * 8], &Bs[0][cid * 8]);
  }
  // boundary xs rows (l0-3..l0-1) via VALU dot (hidden under gl_lds latency)
  if (isconv && tid < 192) {
    int r = tid >> 6, m = tid & 63;
    int lg = l0 - 3 + r;
    float acc = 0.f;
    if (lg >= 0) {
      const ushort* wr = &Wb[(size_t)(m0 + m) * K];
      const ushort* tr = &Act[(size_t)lg * 128];
      for (int k = 0; k < 128; k += 8) {
        short8v wv = *(const short8v*)&wr[k];
        short8v tv = *(const short8v*)&tr[k];
        #pragma unroll
        for (int j = 0; j < 8; ++j)
          acc = fmaf(bf2f((ushort)wv[j]), bf2f((ushort)tv[j]), acc);
      }
    }
    bnd[r * 64 + m] = f2bf(acc);
  }
  float4v acc[4][2];
  #pragma unroll
  for (int a = 0; a < 4; ++a)
    #pragma unroll
    for (int b = 0; b < 2; ++b) acc[a][b] = (float4v)0.f;
  const int w = tid >> 6, lane = tid & 63;
  const int r = lane & 15, g = lane >> 4;
  int buf = 0;
  __syncthreads();
  for (int k0 = 0; k0 < K; k0 += 64) {
    if (k0 + 64 < K) {
      #pragma unroll
      for (int i = 0; i < 4; ++i) {
        int cid = i * 256 + tid;
        int l = cid >> 3, oct = (cid & 7) ^ (l & 7);
        gl_lds16(&Act[(size_t)(l0 + l) * 128 + (k0 + 64) + oct * 8],
                 &Bs[buf ^ 1][cid * 8]);
      }
    }
    const ushort* bp = Bs[buf];
    #pragma unroll
    for (int kk = 0; kk < 2; ++kk) {
      short8v af[4], bfv[2];
      int ko = (k0 >> 3) + kk * 4 + g;
      #pragma unroll
      for (int mf = 0; mf < 4; ++mf) {
        int row = mf * 16 + r;
        af[mf] = *(const short8v*)&As[row * K + ((ko ^ (row & 7)) * 8)];
      }
      int kob = kk * 4 + g;
      #pragma unroll
      for (int nf = 0; nf < 2; ++nf) {
        int row = w * 32 + nf * 16 + r;
        bfv[nf] = *(const short8v*)&bp[row * 64 + ((kob ^ (row & 7)) * 8)];
      }
      #pragma unroll
      for (int mf = 0; mf < 4; ++mf)
        #pragma unroll
        for (int nf = 0; nf < 2; ++nf)
          acc[mf][nf] = __builtin_amdgcn_mfma_f32_16x16x32_bf16(af[mf], bfv[nf], acc[mf][nf], 0, 0, 0);
    }
    __syncthreads();
    buf ^= 1;
  }
  // dump [l][m] bf16 tile into Bs[0] (swizzled)
  #pragma unroll
  for (int mf = 0; mf < 4; ++mf) {
    #pragma unroll
    for (int nf = 0; nf < 2; ++nf) {
      int l = w * 32 + nf * 16 + r;
      int m = mf * 16 + g * 4;
      ushort u0 = f2bf(acc[mf][nf][0]), u1 = f2bf(acc[mf][nf][1]);
      ushort u2 = f2bf(acc[mf][nf][2]), u3 = f2bf(acc[mf][nf][3]);
      uint2 pk = make_uint2((uint)u0 | ((uint)u1 << 16), (uint)u2 | ((uint)u3 << 16));
      int oct = (m >> 3) ^ (l & 7);
      *(uint2*)&Bs[0][l * 64 + oct * 8 + (g & 1) * 4] = pk;
    }
  }
  __syncthreads();
  if (isconv) {
    const int oct_ = tid & 7;
    const int dbase = m0 + oct_ * 8;
    float w0[8], w1[8], w2[8], w3[8], bb8[8];
    #pragma unroll
    for (int j = 0; j < 8; ++j) {
      float4 wv = *(const float4*)&cw[(dbase + j) * 4];
      w0[j] = wv.x; w1[j] = wv.y; w2[j] = wv.z; w3[j] = wv.w;
      bb8[j] = cb[dbase + j];
    }
    #pragma unroll
    for (int i = 0; i < 4; ++i) {
      int cid = i * 256 + tid;
      int row = cid >> 3, oct = cid & 7;
      short8v s[4];
      #pragma unroll
      for (int t = 0; t < 4; ++t) {
        int rr = row - 3 + t;
        if (rr >= 0)
          s[t] = *(const short8v*)&Bs[0][rr * 64 + ((oct ^ (rr & 7)) * 8)];
        else
          s[t] = *(const short8v*)&bnd[(rr + 3) * 64 + oct * 8];
      }
      short8v ov;
      #pragma unroll
      for (int j = 0; j < 8; ++j) {
        float a = bb8[j] + w0[j] * bf2f((ushort)s[0][j]) + w1[j] * bf2f((ushort)s[1][j])
                         + w2[j] * bf2f((ushort)s[2][j]) + w3[j] * bf2f((ushort)s[3][j]);
        ov[j] = (short)f2bf(a / (1.f + __expf(-a)));
      }
      *(short8v*)&xa[(size_t)(l0 + row) * 256 + m0 + oct * 8] = ov;
    }
  } else {
    #pragma unroll
    for (int i = 0; i < 4; ++i) {
      int cid = i * 256 + tid;
      int row = cid >> 3, oct = cid & 7;
      short8v v = *(const short8v*)&Bs[0][row * 64 + ((oct ^ (row & 7)) * 8)];
      *(short8v*)&zt[(size_t)(l0 + row) * 256 + (m0 - 256) + oct * 8] = v;
    }
  }
}

// ---------------- x_proj GEMM: per-kstep dbuf A (8KB x2) + dbuf B (16KB x2) = 48KB ----------------
template<int K, int MV, int BSTR, int CSTR>
__global__ __launch_bounds__(256) void gemm_tok(
    const ushort* __restrict__ Wb,
    const ushort* __restrict__ Act,
    ushort* __restrict__ Out) {
  __shared__ ushort As[2][64 * 64];
  __shared__ ushort Bs[2][128 * 64];
  const int tid = threadIdx.x;
  const int l0 = blockIdx.x * 128;
  const int m0 = blockIdx.y * 64;
  // issue A0 + B0 via gl_lds (linear dest, inverse-swizzled source)
  #pragma unroll
  for (int i = 0; i < 2; ++i) {
    int cid = i * 256 + tid;
    int m = cid >> 3, oct = (cid & 7) ^ (m & 7);
    gl_lds16(&Wb[(size_t)(m0 + m) * K + oct * 8], &As[0][cid * 8]);
  }
  #pragma unroll
  for (int i = 0; i < 4; ++i) {
    int cid = i * 256 + tid;
    int l = cid >> 3, oct = (cid & 7) ^ (l & 7);
    gl_lds16(&Act[(size_t)(l0 + l) * BSTR + oct * 8], &Bs[0][cid * 8]);
  }
  float4v acc[4][2];
  #pragma unroll
  for (int a = 0; a < 4; ++a)
    #pragma unroll
    for (int b = 0; b < 2; ++b) acc[a][b] = (float4v)0.f;
  const int w = tid >> 6, lane = tid & 63;
  const int r = lane & 15, g = lane >> 4;
  int buf = 0;
  __syncthreads();
  for (int k0 = 0; k0 < K; k0 += 64) {
    if (k0 + 64 < K) {
      #pragma unroll
      for (int i = 0; i < 2; ++i) {
        int cid = i * 256 + tid;
        int m = cid >> 3, oct = (cid & 7) ^ (m & 7);
        gl_lds16(&Wb[(size_t)(m0 + m) * K + (k0 + 64) + oct * 8], &As[buf ^ 1][cid * 8]);
      }
      #pragma unroll
      for (int i = 0; i < 4; ++i) {
        int cid = i * 256 + tid;
        int l = cid >> 3, oct = (cid & 7) ^ (l & 7);
        gl_lds16(&Act[(size_t)(l0 + l) * BSTR + (k0 + 64) + oct * 8],
                 &Bs[buf ^ 1][cid * 8]);
      }
    }
    const ushort* ap = As[buf];
    const ushort* bp = Bs[buf];
    #pragma unroll
    for (int kk = 0; kk < 2; ++kk) {
      short8v af[4], bfv[2];
      int kob = kk * 4 + g;
      #pragma unroll
      for (int mf = 0; mf < 4; ++mf) {
        int row = mf * 16 + r;
        af[mf] = *(const short8v*)&ap[row * 64 + ((kob ^ (row & 7)) * 8)];
      }
      #pragma unroll
      for (int nf = 0; nf < 2; ++nf) {
        int row = w * 32 + nf * 16 + r;
        bfv[nf] = *(const short8v*)&bp[row * 64 + ((kob ^ (row & 7)) * 8)];
      }
      #pragma unroll
      for (int mf = 0; mf < 4; ++mf)
        #pragma unroll
        for (int nf = 0; nf < 2; ++nf)
          acc[mf][nf] = __builtin_amdgcn_mfma_f32_16x16x32_bf16(af[mf], bfv[nf], acc[mf][nf], 0, 0, 0);
    }
    __syncthreads();
    buf ^= 1;
  }
  #pragma unroll
  for (int mf = 0; mf < 4; ++mf) {
    #pragma unroll
    for (int nf = 0; nf < 2; ++nf) {
      int l = w * 32 + nf * 16 + r;
      int m = mf * 16 + g * 4;
      ushort u0 = f2bf(acc[mf][nf][0]), u1 = f2bf(acc[mf][nf][1]);
      ushort u2 = f2bf(acc[mf][nf][2]), u3 = f2bf(acc[mf][nf][3]);
      uint2 pk = make_uint2((uint)u0 | ((uint)u1 << 16), (uint)u2 | ((uint)u3 << 16));
      int oct = (m >> 3) ^ (l & 7);
      *(uint2*)&Bs[0][l * 64 + oct * 8 + (g & 1) * 4] = pk;
    }
  }
  __syncthreads();
  #pragma unroll
  for (int i = 0; i < 4; ++i) {
    int cid = i * 256 + tid;
    int row = cid >> 3, oct = cid & 7;
    if (oct * 8 < MV) {
      short8v v = *(const short8v*)&Bs[0][row * 64 + ((oct ^ (row & 7)) * 8)];
      *(short8v*)&Out[(size_t)(l0 + row) * CSTR + m0 + oct * 8] = v;
    }
  }
}

// ---------------- out_proj GEMM (swapped operands) + fp32 residual, 48KB LDS ----------------
__global__ __launch_bounds__(256) void gemm_out_k(
    const ushort* __restrict__ Wb,
    const ushort* __restrict__ Yg,    // 16 slabs of (L,16) bf16
    const float* __restrict__ X,
    float* __restrict__ Out) {
  __shared__ ushort Ay[2][128 * 64];
  __shared__ ushort Bw[2][64 * 64];
  const int tid = threadIdx.x;
  const int l0 = blockIdx.x * 128;
  const int c0 = blockIdx.y * 64;
  const int w = tid >> 6, lane = tid & 63;
  const int r = lane & 15, g = lane >> 4;
  // issue Bw0 + Ay0
  #pragma unroll
  for (int i = 0; i < 2; ++i) {
    int cid = i * 256 + tid;
    int row = cid >> 3, oct = (cid & 7) ^ (row & 7);
    gl_lds16(&Wb[(size_t)(c0 + row) * 256 + oct * 8], &Bw[0][cid * 8]);
  }
  #pragma unroll
  for (int i = 0; i < 4; ++i) {
    int cid = i * 256 + tid;
    int row = cid >> 3, oct = (cid & 7) ^ (row & 7);
    gl_lds16(&Yg[((size_t)(oct >> 1) * LQ + l0 + row) * 16 + (oct & 1) * 8],
             &Ay[0][cid * 8]);
  }
  float4v acc[2][4];
  #pragma unroll
  for (int a = 0; a < 2; ++a)
    #pragma unroll
    for (int b = 0; b < 4; ++b) acc[a][b] = (float4v)0.f;
  int buf = 0;
  __syncthreads();
  for (int k0 = 0; k0 < 256; k0 += 64) {
    if (k0 + 64 < 256) {
      int ks = (k0 + 64) >> 4;
      #pragma unroll
      for (int i = 0; i < 2; ++i) {
        int cid = i * 256 + tid;
        int row = cid >> 3, oct = (cid & 7) ^ (row & 7);
        gl_lds16(&Wb[(size_t)(c0 + row) * 256 + (k0 + 64) + oct * 8], &Bw[buf ^ 1][cid * 8]);
      }
      #pragma unroll
      for (int i = 0; i < 4; ++i) {
        int cid = i * 256 + tid;
        int row = cid >> 3, oct = (cid & 7) ^ (row & 7);
        gl_lds16(&Yg[((size_t)(ks + (oct >> 1)) * LQ + l0 + row) * 16 + (oct & 1) * 8],
                 &Ay[buf ^ 1][cid * 8]);
      }
    }
    const ushort* ap = Ay[buf];
    const ushort* bp = Bw[buf];
    #pragma unroll
    for (int kk = 0; kk < 2; ++kk) {
      int kob = kk * 4 + g;
      short8v af[2], bfv[4];
      #pragma unroll
      for (int mf = 0; mf < 2; ++mf) {
        int row = w * 32 + mf * 16 + r;
        af[mf] = *(const short8v*)&ap[row * 64 + ((kob ^ (row & 7)) * 8)];
      }
      #pragma unroll
      for (int nf = 0; nf < 4; ++nf) {
        int row = nf * 16 + r;
        bfv[nf] = *(const short8v*)&bp[row * 64 + ((kob ^ (row & 7)) * 8)];
      }
      #pragma unroll
      for (int mf = 0; mf < 2; ++mf)
        #pragma unroll
        for (int nf = 0; nf < 4; ++nf)
          acc[mf][nf] = __builtin_amdgcn_mfma_f32_16x16x32_bf16(af[mf], bfv[nf], acc[mf][nf], 0, 0, 0);
    }
    __syncthreads();
    buf ^= 1;
  }
  #pragma unroll
  for (int mf = 0; mf < 2; ++mf) {
    #pragma unroll
    for (int nf = 0; nf < 4; ++nf) {
      int c = c0 + nf * 16 + r;
      int l = l0 + w * 32 + mf * 16 + g * 4;
      size_t off = (size_t)c * LQ + l;
      float4 rv = *(const float4*)&X[off];
      float4 o = make_float4(acc[mf][nf][0] + rv.x, acc[mf][nf][1] + rv.y,
                             acc[mf][nf][2] + rv.z, acc[mf][nf][3] + rv.w);
      *(float4*)&Out[off] = o;
    }
  }
}

// ---------------- scan pass 1: local scan, 4 states/thread, CH=64 ----------------
__global__ __launch_bounds__(256) void scan1(const ushort* __restrict__ xdbl,
    const ushort* __restrict__ xa, const float* __restrict__ bias,
    const float* __restrict__ A_log, float* __restrict__ Stot, float* __restrict__ Hc,
    ushort* __restrict__ yloc) {
  __shared__ uint  duL[64 * 64];    // [i][d] (dt lo | dt*xa hi)        16 KB
  __shared__ float bcL[64 * 32];    // [i][B0..15 C16..31] fp32          8 KB
  __shared__ ushort ylds[64 * 72];  // [i][d] y bf16 (pad 72)          9.2 KB
  const int tid = threadIdx.x;
  const int c = blockIdx.x, dg = blockIdx.y;
  const int dloc = tid >> 2, sq = tid & 3;
  const int d = dg * 64 + dloc;
  const int lb = c * CH;
  float4v A, h;
  #pragma unroll
  for (int k = 0; k < 4; ++k) {
    A[k] = -__expf(A_log[d * 16 + sq * 4 + k]);
    h[k] = 0.f;
  }
  float S = 0.f;
  {   // stage (dt, dt*xa)
    const int doff = dg * 64 + sq * 16;
    const ushort* xr = xdbl + (size_t)(lb + dloc) * 320 + 32 + doff;
    const ushort* xar = xa + (size_t)(lb + dloc) * 256 + doff;
    short8v d0 = *(const short8v*)xr;
    short8v d1 = *(const short8v*)(xr + 8);
    short8v x0 = *(const short8v*)xar;
    short8v x1 = *(const short8v*)(xar + 8);
    uint pk[16];
    #pragma unroll
    for (int j = 0; j < 8; ++j) {
      float sp = softplus_f(bf2f((ushort)d0[j]) + bias[doff + j]);
      pk[j] = (uint)f2bf(sp) | ((uint)f2bf(sp * bf2f((ushort)x0[j])) << 16);
      float sp2 = softplus_f(bf2f((ushort)d1[j]) + bias[doff + 8 + j]);
      pk[8 + j] = (uint)f2bf(sp2) | ((uint)f2bf(sp2 * bf2f((ushort)x1[j])) << 16);
    }
    uint4* dst = (uint4*)&duL[dloc * 64 + sq * 16];
    #pragma unroll
    for (int j = 0; j < 4; ++j)
      dst[j] = make_uint4(pk[4 * j], pk[4 * j + 1], pk[4 * j + 2], pk[4 * j + 3]);
  }
  if (tid < 128) {  // stage B, C as fp32
    int row = tid >> 1, half = tid & 1;
    const ushort* xr = xdbl + (size_t)(lb + row) * 320;
    short8v bv = *(const short8v*)(xr + half * 8);
    short8v cv = *(const short8v*)(xr + 16 + half * 8);
    float* bd = &bcL[row * 32 + half * 8];
    float* cd = &bcL[row * 32 + 16 + half * 8];
    #pragma unroll
    for (int j = 0; j < 8; ++j) {
      bd[j] = bf2f((ushort)bv[j]);
      cd[j] = bf2f((ushort)cv[j]);
    }
  }
  __syncthreads();
  #pragma unroll 4
  for (int i = 0; i < CH; ++i) {
    uint pv = duL[i * 64 + dloc];
    float dtv = __uint_as_float(pv << 16);
    float dxv = __uint_as_float(pv & 0xffff0000u);
    S += dtv;
    float4v Bv = *(const float4v*)&bcL[i * 32 + sq * 4];
    float4v Cv = *(const float4v*)&bcL[i * 32 + 16 + sq * 4];
    float t = 0.f;
    #pragma unroll
    for (int k = 0; k < 4; ++k) {
      float a = __expf(dtv * A[k]);
      h[k] = fmaf(a, h[k], dxv * Bv[k]);
      t = fmaf(h[k], Cv[k], t);
    }
    t = quad_reduce(t);
    if (sq == 0) ylds[i * 72 + dloc] = f2bf(t);
  }
  __syncthreads();
  {   // flush y -> slabs
    int slab = tid >> 6, row = tid & 63;
    short8v v0 = *(const short8v*)&ylds[row * 72 + slab * 16];
    short8v v1 = *(const short8v*)&ylds[row * 72 + slab * 16 + 8];
    ushort* dst = &yloc[((size_t)(dg * 4 + slab) * LQ + lb + row) * 16];
    *(short8v*)dst = v0;
    *(short8v*)(dst + 8) = v1;
  }
  *(float4*)&Hc[(size_t)(c * 256 + d) * 16 + sq * 4] = make_float4(h[0], h[1], h[2], h[3]);
  if (sq == 0) Stot[c * 256 + d] = S;
}

// ---------------- scan combine: serial over chunks, batch-8 load pipeline ----------------
__global__ __launch_bounds__(256) void scan_combine(const float* __restrict__ Stot,
    const float* __restrict__ Hc, const float* __restrict__ A_log,
    float* __restrict__ Hin) {
  int t = blockIdx.x * 256 + threadIdx.x;   // d*16 + s
  int d = t >> 4;
  float A = -__expf(A_log[t]);
  float h = 0.f;
  for (int cb = 0; cb < NC; cb += 8) {
    float a[8], b[8];
    #pragma unroll
    for (int j = 0; j < 8; ++j) {          // independent loads, issue together
      a[j] = Stot[(cb + j) * 256 + d];
      b[j] = Hc[(size_t)(cb + j) * 4096 + t];
    }
    #pragma unroll
    for (int j = 0; j < 8; ++j) {          // dependent chain
      Hin[(size_t)(cb + j) * 4096 + t] = h;
      h = fmaf(__expf(A * a[j]), h, b[j]);
    }
  }
}

// ---------------- scan pass 2: parallel correction + gate, corr in bf16 (21.2 KB LDS) ----------------
__global__ __launch_bounds__(256) void scan2(const ushort* __restrict__ xdbl,
    const ushort* __restrict__ xa, const ushort* __restrict__ zt,
    const float* __restrict__ bias, const float* __restrict__ A_log,
    const float* __restrict__ Dp, const float* __restrict__ Hin,
    ushort* __restrict__ yg) {
  __shared__ uint  dtp[32 * 64];    // [i2][d] (dt even lo | odd hi)     8 KB
  __shared__ float cL[64 * 16];     // [i][C0..15] fp32                  4 KB
  __shared__ ushort corr[64 * 72];  // [i][d] bf16 (pad 72)            9.2 KB
  const int tid = threadIdx.x;
  const int c = blockIdx.x, dg = blockIdx.y;
  const int dloc = tid >> 2, sq = tid & 3;
  const int d = dg * 64 + dloc;
  const int lb = c * CH;
  float4v A, hin;
  #pragma unroll
  for (int k = 0; k < 4; ++k) A[k] = -__expf(A_log[d * 16 + sq * 4 + k]);
  {
    float4 hv = *(const float4*)&Hin[(size_t)(c * 256 + d) * 16 + sq * 4];
    hin[0] = hv.x; hin[1] = hv.y; hin[2] = hv.z; hin[3] = hv.w;
  }
  float S = 0.f;
  {   // stage dt pairs
    int rp = tid >> 3, seg = tid & 7;
    const int doff = dg * 64 + seg * 8;
    const ushort* xr0 = xdbl + (size_t)(lb + 2 * rp) * 320 + 32 + doff;
    short8v e0 = *(const short8v*)xr0;
    short8v e1 = *(const short8v*)(xr0 + 320);
    uint pk[8];
    #pragma unroll
    for (int j = 0; j < 8; ++j) {
      float spe = softplus_f(bf2f((ushort)e0[j]) + bias[doff + j]);
      float spo = softplus_f(bf2f((ushort)e1[j]) + bias[doff + j]);
      pk[j] = (uint)f2bf(spe) | ((uint)f2bf(spo) << 16);
    }
    uint4* dst = (uint4*)&dtp[rp * 64 + seg * 8];
    dst[0] = make_uint4(pk[0], pk[1], pk[2], pk[3]);
    dst[1] = make_uint4(pk[4], pk[5], pk[6], pk[7]);
  }
  if (tid < 128) {  // stage C fp32
    int row = tid >> 1, half = tid & 1;
    short8v cv = *(const short8v*)(xdbl + (size_t)(lb + row) * 320 + 16 + half * 8);
    float* cd = &cL[row * 16 + half * 8];
    #pragma unroll
    for (int j = 0; j < 8; ++j) cd[j] = bf2f((ushort)cv[j]);
  }
  __syncthreads();
  #pragma unroll 2
  for (int i2 = 0; i2 < CH / 2; ++i2) {
    uint pv = dtp[i2 * 64 + dloc];
    #pragma unroll
    for (int par = 0; par < 2; ++par) {
      float dtv = (par == 0) ? __uint_as_float(pv << 16)
                             : __uint_as_float(pv & 0xffff0000u);
      S += dtv;
      int i = i2 * 2 + par;
      float4v Cv = *(const float4v*)&cL[i * 16 + sq * 4];
      float t = 0.f;
      #pragma unroll
      for (int k = 0; k < 4; ++k)
        t = fmaf(__expf(A[k] * S), hin[k] * Cv[k], t);
      t = quad_reduce(t);
      if (sq == 0) corr[i * 72 + dloc] = f2bf(t);
    }
  }
  __syncthreads();
  {   // flush: y = (yloc + corr + xa*D) * silu(z)
    int slab = tid >> 6, row = tid & 63;
    const int doff = dg * 64 + slab * 16;
    size_t sl = ((size_t)(dg * 4 + slab) * LQ + lb + row) * 16;
    short8v y0 = *(const short8v*)&yg[sl];
    short8v y1 = *(const short8v*)&yg[sl + 8];
    const ushort* xav = xa + (size_t)(lb + row) * 256 + doff;
    short8v x0 = *(const short8v*)xav;
    short8v x1 = *(const short8v*)(xav + 8);
    const ushort* zvp = zt + (size_t)(lb + row) * 256 + doff;
    short8v z0 = *(const short8v*)zvp;
    short8v z1 = *(const short8v*)(zvp + 8);
    short8v c0 = *(const short8v*)&corr[row * 72 + slab * 16];
    short8v c1 = *(const short8v*)&corr[row * 72 + slab * 16 + 8];
    short8v o0, o1;
    #pragma unroll
    for (int j = 0; j < 8; ++j) {
      float v0 = bf2f((ushort)y0[j]) + bf2f((ushort)c0[j]) + bf2f((ushort)x0[j]) * Dp[doff + j];
      float zf0 = bf2f((ushort)z0[j]);
      o0[j] = (short)f2bf(v0 * (zf0 / (1.f + __expf(-zf0))));
      float v1 = bf2f((ushort)y1[j]) + bf2f((ushort)c1[j]) + bf2f((ushort)x1[j]) * Dp[doff + 8 + j];
      float zf1 = bf2f((ushort)z1[j]);
      o1[j] = (short)f2bf(v1 * (zf1 / (1.f + __expf(-zf1))));
    }
    *(short8v*)&yg[sl] = o0;
    *(short8v*)&yg[sl + 8] = o1;
  }
}

extern "C" void kernel_launch(void* const* d_in, const int* in_sizes, int n_in,
                              void* d_out, int out_size, void* d_ws, size_t ws_size,
                              hipStream_t stream) {
  const float* x         = (const float*)d_in[0];
  const float* ln_w      = (const float*)d_in[1];
  const float* ln_b      = (const float*)d_in[2];
  const float* in_proj_w = (const float*)d_in[3];
  const float* conv_w    = (const float*)d_in[4];
  const float* conv_b    = (const float*)d_in[5];
  const float* x_proj_w  = (const float*)d_in[6];
  const float* dt_proj_w = (const float*)d_in[7];
  const float* dt_proj_b = (const float*)d_in[8];
  const float* A_log     = (const float*)d_in[9];
  const float* D_param   = (const float*)d_in[10];
  const float* out_proj_w= (const float*)d_in[11];
  float* out = (float*)d_out;

  char* ws = (char*)d_ws;
  ushort* wbf_in  = (ushort*)(ws + 0);           // 512x128
  ushort* wbf_xp2 = (ushort*)(ws + 131072);      // 320x256
  ushort* wbf_out = (ushort*)(ws + 294912);      // 128x256
  float*  Hin     = (float*)(ws + 360448);       // 216x4096
  float*  Hc      = (float*)(ws + 3899392);      // 216x4096
  float*  Stot    = (float*)(ws + 7438336);      // 216x256
  ushort* tn_t    = (ushort*)(ws + 7659520);     // (L,128)
  ushort* zt      = (ushort*)(ws + 11198464);    // (L,256) gate z
  ushort* xa_t    = (ushort*)(ws + 18276352);    // (L,256)
  ushort* xdbl_t  = (ushort*)(ws + 25354240);    // (L,320): B 0..15, C 16..31, dt_lin 32..287
  ushort* yg_t    = (ushort*)(ws + 34201600);    // 16 slabs (L,16)

  prep_ln<<<920, 256, 0, stream>>>(in_proj_w, x_proj_w, dt_proj_w, out_proj_w,
                                   x, ln_w, ln_b, wbf_in, wbf_xp2, wbf_out, tn_t);
  gemm_in_conv<<<dim3(NB, 8), 256, 0, stream>>>(wbf_in, tn_t, conv_w, conv_b, xa_t, zt);
  gemm_tok<256, 64, 256, 320><<<dim3(NB, 5), 256, 0, stream>>>(wbf_xp2, xa_t, xdbl_t);
  scan1<<<dim3(NC, 4), 256, 0, stream>>>(xdbl_t, xa_t, dt_proj_b, A_log, Stot, Hc, yg_t);
  scan_combine<<<16, 256, 0, stream>>>(Stot, Hc, A_log, Hin);
  scan2<<<dim3(NC, 4), 256, 0, stream>>>(xdbl_t, xa_t, zt, dt_proj_b, A_log,
                                         D_param, Hin, yg_t);
  gemm_out_k<<<dim3(NB, 2), 256, 0, stream>>>(wbf_out, yg_t, x, out);
}